// Round 5
// baseline (390.032 us; speedup 1.0000x reference)
//
#include <hip/hip_runtime.h>
#include <hip/hip_bf16.h>
#include <float.h>
#include <math.h>

// dims
#define BB   4
#define SS   16
#define TQN  2048
#define DD   768
#define NTT  64
#define NKK  1024     // SS*NTT
#define MID1 204
#define MID2 409

typedef float nt_f4 __attribute__((ext_vector_type(4)));  // native vec for nontemporal builtin

// ---------------------------------------------------------------------------
// K1: fused  testM = mean_s(reps)  AND  U[b,s,q] = sup[b,s,:].testM[b,q,:]
// One block per (b,q). The 403 MB reps read is the HBM floor (~64 us).
// sup (196 KB) is L2-resident; dot work hides under the memory latency.
// ---------------------------------------------------------------------------
__global__ __launch_bounds__(192) void k_mean_u(const nt_f4* __restrict__ reps,
                                                float4* __restrict__ testM,
                                                const float4* __restrict__ sup,
                                                float* __restrict__ U) {
    const int QD4 = TQN * DD / 4;                 // stride between s-slices
    int bq = blockIdx.x;
    int b = bq >> 11, q = bq & 2047;
    int t = threadIdx.x;                          // 0..191, each owns one float4 of the row
    const nt_f4* base = reps + ((size_t)b * SS * TQN + q) * (DD / 4) + t;
    nt_f4 acc = {0.f, 0.f, 0.f, 0.f};
#pragma unroll
    for (int s = 0; s < SS; ++s)
        acc += __builtin_nontemporal_load(&base[(size_t)s * QD4]);
    acc *= (1.f / SS);
    float4 av; av.x = acc.x; av.y = acc.y; av.z = acc.z; av.w = acc.w;
    testM[((size_t)b * TQN + q) * (DD / 4) + t] = av;

    float part[SS];
#pragma unroll
    for (int s = 0; s < SS; ++s) {
        float4 sv = sup[((size_t)b * SS + s) * (DD / 4) + t];
        part[s] = av.x * sv.x + av.y * sv.y + av.z * sv.z + av.w * sv.w;
    }
    __shared__ float rbuf[3][SS];
    int lane = t & 63, wv = t >> 6;
#pragma unroll
    for (int s = 0; s < SS; ++s) {
        float v = part[s];
        for (int o = 32; o; o >>= 1) v += __shfl_down(v, o, 64);
        if (lane == 0) rbuf[wv][s] = v;
    }
    __syncthreads();
    if (t < SS)
        U[((size_t)b * SS + t) * TQN + q] = rbuf[0][t] + rbuf[1][t] + rbuf[2][t];
}

// ---------------------------------------------------------------------------
// K2: per-(b,s) stats of U over q, and of tgt over n
// ---------------------------------------------------------------------------
__global__ __launch_bounds__(256) void k_stats(const float* __restrict__ U,
                                               const float* __restrict__ tgt,
                                               float* __restrict__ Umax, float* __restrict__ Umin,
                                               float* __restrict__ Usum,
                                               float* __restrict__ cmax, float* __restrict__ cmin,
                                               float* __restrict__ csum) {
    int bs = blockIdx.x, t = threadIdx.x;
    const float* u = U + (size_t)bs * TQN;
    float mx = -FLT_MAX, mn = FLT_MAX, sm = 0.f;
    for (int q = t; q < TQN; q += 256) {
        float v = u[q];
        mx = fmaxf(mx, v); mn = fminf(mn, v); sm += v;
    }
    int lane = t & 63, wv = t >> 6;
    for (int o = 32; o; o >>= 1) {
        mx = fmaxf(mx, __shfl_down(mx, o, 64));
        mn = fminf(mn, __shfl_down(mn, o, 64));
        sm += __shfl_down(sm, o, 64);
    }
    __shared__ float smx[4], smn[4], ssm[4];
    if (lane == 0) { smx[wv] = mx; smn[wv] = mn; ssm[wv] = sm; }
    __syncthreads();
    if (t == 0) {
        Umax[bs] = fmaxf(fmaxf(smx[0], smx[1]), fmaxf(smx[2], smx[3]));
        Umin[bs] = fminf(fminf(smn[0], smn[1]), fminf(smn[2], smn[3]));
        Usum[bs] = ssm[0] + ssm[1] + ssm[2] + ssm[3];
    }
    if (wv == 1) {  // wave 1 handles the 64 tgt values
        float v = tgt[(size_t)bs * NTT + lane];
        float tmx = v, tmn = v, tsm = v;
        for (int o = 32; o; o >>= 1) {
            tmx = fmaxf(tmx, __shfl_down(tmx, o, 64));
            tmn = fminf(tmn, __shfl_down(tmn, o, 64));
            tsm += __shfl_down(tsm, o, 64);
        }
        if (lane == 0) { cmax[bs] = tmx; cmin[bs] = tmn; csum[bs] = tsm; }
    }
}

// ---------------------------------------------------------------------------
// K3: BOTH hidden layers in one launch.
// blocks [0, BB*4)           -> branch 1 (NIN=1024, NH=204, feature from tgt stats)
// blocks [BB*4, BB*4+BB*7)   -> branch 2 (NIN=2048, NH=409, feature from U cols)
// 4 waves split the reduction; lanes own 64 consecutive outputs.
// ---------------------------------------------------------------------------
__global__ __launch_bounds__(256) void k_mlp_h(const float* __restrict__ tgt,
                                               const float* __restrict__ Umax,
                                               const float* __restrict__ Umin,
                                               const float* __restrict__ Usum,
                                               const float* __restrict__ U,
                                               const float* __restrict__ cmax,
                                               const float* __restrict__ cmin,
                                               const float* __restrict__ csum,
                                               const float* __restrict__ w1a,
                                               const float* __restrict__ b1a,
                                               const float* __restrict__ w1b,
                                               const float* __restrict__ b1b,
                                               float* __restrict__ h1m, float* __restrict__ h1a,
                                               float* __restrict__ h2m, float* __restrict__ h2a) {
    int blk = blockIdx.x;
    int t = threadIdx.x, lane = t & 63, wv = t >> 6;
    __shared__ float sm[TQN], sa[TQN];

    int b, j0, NIN, NH;
    const float *w1, *b1;
    float *hm, *ha;
    if (blk < BB * 4) {              // ---- branch 1
        b = blk >> 2; j0 = (blk & 3) * 64;
        NIN = NKK; NH = MID1; w1 = w1a; b1 = b1a; hm = h1m; ha = h1a;
        for (int i = t; i < NKK; i += 256) {
            int bs = b * SS + (i >> 6);
            float c = tgt[b * NKK + i];
            sm[i] = c > 0.f ? c * Umax[bs] : (c < 0.f ? c * Umin[bs] : 0.f);
            sa[i] = c * Usum[bs] * (1.f / TQN);
        }
    } else {                         // ---- branch 2
        int blk2 = blk - BB * 4;
        b = blk2 / 7; j0 = (blk2 % 7) * 64;
        NIN = TQN; NH = MID2; w1 = w1b; b1 = b1b; hm = h2m; ha = h2a;
        for (int i = t; i < TQN; i += 256) {
            float vmax = -FLT_MAX, vsum = 0.f;
#pragma unroll
            for (int s = 0; s < SS; ++s) {
                int bs = b * SS + s;
                float u = U[(size_t)bs * TQN + i];
                float pm_ = u > 0.f ? u * cmax[bs] : (u < 0.f ? u * cmin[bs] : 0.f);
                vmax = fmaxf(vmax, pm_);
                vsum += u * csum[bs];
            }
            sm[i] = vmax;
            sa[i] = vsum * (1.f / NKK);
        }
    }
    __syncthreads();
    int j = j0 + lane;
    float accm = 0.f, acca = 0.f;
    int rq = NIN >> 2;
    int r0 = wv * rq, r1 = r0 + rq;
    if (j < NH) {
        for (int r = r0; r < r1; ++r) {
            float w = w1[(size_t)r * NH + j];
            accm += sm[r] * w;
            acca += sa[r] * w;
        }
    }
    __shared__ float pm[4][64], pa[4][64];
    pm[wv][lane] = accm; pa[wv][lane] = acca;
    __syncthreads();
    if (t < 64 && j0 + t < NH) {
        float bb_ = b1[j0 + t];
        float m_ = pm[0][t] + pm[1][t] + pm[2][t] + pm[3][t] + bb_;
        float a_ = pa[0][t] + pa[1][t] + pa[2][t] + pa[3][t] + bb_;
        hm[b * NH + j0 + t] = fmaxf(m_, 0.f);
        ha[b * NH + j0 + t] = fmaxf(a_, 0.f);
    }
}

// ---------------------------------------------------------------------------
// K4: BOTH out layers + fuse MLP in one launch -> y (pre-softmax)
// blocks [0, BB*8)  -> branch 1 (NH=204, NOUT=1024)
// blocks [BB*8, BB*8+BB*16) -> branch 2 (NH=409, NOUT=2048)
// ---------------------------------------------------------------------------
__global__ __launch_bounds__(256) void k_mlp_out(const float* __restrict__ h1m,
                                                 const float* __restrict__ h1a,
                                                 const float* __restrict__ h2m,
                                                 const float* __restrict__ h2a,
                                                 const float* __restrict__ w2a,
                                                 const float* __restrict__ b2a,
                                                 const float* __restrict__ w2b,
                                                 const float* __restrict__ b2b,
                                                 const float* __restrict__ fw1, const float* __restrict__ fb1,
                                                 const float* __restrict__ fw2, const float* __restrict__ fb2,
                                                 float* __restrict__ y1, float* __restrict__ y2) {
    int blk = blockIdx.x;
    int t = threadIdx.x;
    int b, r0, NH, NOUT;
    const float *hm_, *ha_, *w2, *b2;
    float* y;
    if (blk < BB * 8) {
        b = blk >> 3; r0 = (blk & 7) * 128;
        NH = MID1; NOUT = NKK; hm_ = h1m; ha_ = h1a; w2 = w2a; b2 = b2a; y = y1;
    } else {
        int blk2 = blk - BB * 8;
        b = blk2 >> 4; r0 = (blk2 & 15) * 128;
        NH = MID2; NOUT = TQN; hm_ = h2m; ha_ = h2a; w2 = w2b; b2 = b2b; y = y2;
    }
    int rl = t & 127, jp = t >> 7;
    __shared__ float shm[512], sha[512];
    for (int i = t; i < NH; i += 256) { shm[i] = hm_[b * NH + i]; sha[i] = ha_[b * NH + i]; }
    __syncthreads();
    float accm = 0.f, acca = 0.f;
    for (int j = jp; j < NH; j += 2) {
        float w = w2[(size_t)j * NOUT + r0 + rl];
        accm += shm[j] * w; acca += sha[j] * w;
    }
    __shared__ float qm[2][128], qa[2][128];
    qm[jp][rl] = accm; qa[jp][rl] = acca;
    __syncthreads();
    if (t < 128) {
        float bb_ = b2[r0 + t];
        float ym = qm[0][t] + qm[1][t] + bb_;
        float ya = qa[0][t] + qa[1][t] + bb_;
        float z = fmaxf(ya * fw1[0] + ym * fw1[1] + fb1[0], 0.f);
        y[b * NOUT + r0 + t] = z * fw2[0] + fb2[0];
    }
}

// ---------------------------------------------------------------------------
// K5: both softmaxes in one launch. blocks 0..3 -> y1 (N=1024), 4..7 -> y2 (2048)
// ---------------------------------------------------------------------------
__global__ __launch_bounds__(256) void k_softmax2(const float* __restrict__ y1,
                                                  float* __restrict__ W1,
                                                  const float* __restrict__ y2,
                                                  float* __restrict__ W2) {
    int blk = blockIdx.x, t = threadIdx.x;
    const float* yr; float* Wr; int N;
    if (blk < BB) { yr = y1 + (size_t)blk * NKK; Wr = W1 + (size_t)blk * NKK; N = NKK; }
    else          { yr = y2 + (size_t)(blk - BB) * TQN; Wr = W2 + (size_t)(blk - BB) * TQN; N = TQN; }
    int lane = t & 63, wv = t >> 6;
    __shared__ float rb[4];
    float mx = -FLT_MAX;
    for (int i = t; i < N; i += 256) mx = fmaxf(mx, yr[i]);
    for (int o = 32; o; o >>= 1) mx = fmaxf(mx, __shfl_down(mx, o, 64));
    if (lane == 0) rb[wv] = mx;
    __syncthreads();
    mx = fmaxf(fmaxf(rb[0], rb[1]), fmaxf(rb[2], rb[3]));
    __syncthreads();
    float sm = 0.f;
    for (int i = t; i < N; i += 256) sm += expf(yr[i] - mx);
    for (int o = 32; o; o >>= 1) sm += __shfl_down(sm, o, 64);
    if (lane == 0) rb[wv] = sm;
    __syncthreads();
    sm = rb[0] + rb[1] + rb[2] + rb[3];
    float inv = 1.f / sm;
    for (int i = t; i < N; i += 256) Wr[i] = expf(yr[i] - mx) * inv + 1.f;
}

// ---------------------------------------------------------------------------
// K6: proto[b,n,:] = (sum_s W1[b,s*64+n]*tgt[b,s,n]*sup[b,s,:]) / (count+1e-4)
// ---------------------------------------------------------------------------
__global__ __launch_bounds__(256) void k_proto(const float* __restrict__ W1,
                                               const float* __restrict__ tgt,
                                               const float* __restrict__ sup,
                                               float* __restrict__ proto) {
    int bn = blockIdx.x;           // [0, BB*NTT)
    int b = bn >> 6, n = bn & 63;
    int t = threadIdx.x;
    float a0 = 0.f, a1 = 0.f, a2 = 0.f, cnt = 0.f;
#pragma unroll
    for (int s = 0; s < SS; ++s) {
        float tg = tgt[((size_t)b * SS + s) * NTT + n];
        float coef = W1[b * NKK + s * NTT + n] * tg;
        const float* sv = sup + ((size_t)b * SS + s) * DD;
        a0 += coef * sv[t];
        a1 += coef * sv[t + 256];
        a2 += coef * sv[t + 512];
        cnt += tg;
    }
    float inv = 1.f / (cnt + 1e-4f);
    float* p = proto + (size_t)bn * DD;
    p[t] = a0 * inv; p[t + 256] = a1 * inv; p[t + 512] = a2 * inv;
}

// ---------------------------------------------------------------------------
// K7: sim[b,q,n] = W2[b,q] * (testM[b,q,:] . proto[b,n,:])
// ---------------------------------------------------------------------------
__global__ __launch_bounds__(256) void k_sim(const float* __restrict__ testM,
                                             const float* __restrict__ proto,
                                             const float* __restrict__ W2,
                                             float* __restrict__ sim) {
    int bq = blockIdx.x;
    int b = bq / (TQN / 32), q0 = (bq % (TQN / 32)) * 32;
    __shared__ float st[32][129];
    __shared__ float sp[64][129];
    int t = threadIdx.x;
    int qi = (t >> 4) * 2;      // 0..30
    int ni = (t & 15) * 4;      // 0..60
    float acc[2][4] = {};
    for (int kc = 0; kc < DD; kc += 128) {
        for (int i = t; i < 32 * 32; i += 256) {      // 32 rows x 32 float4
            int row = i >> 5, c4 = i & 31;
            float4 v = *reinterpret_cast<const float4*>(
                &testM[((size_t)b * TQN + q0 + row) * DD + kc + c4 * 4]);
            st[row][c4 * 4 + 0] = v.x; st[row][c4 * 4 + 1] = v.y;
            st[row][c4 * 4 + 2] = v.z; st[row][c4 * 4 + 3] = v.w;
        }
        for (int i = t; i < 64 * 32; i += 256) {      // 64 rows x 32 float4
            int row = i >> 5, c4 = i & 31;
            float4 v = *reinterpret_cast<const float4*>(
                &proto[((size_t)b * NTT + row) * DD + kc + c4 * 4]);
            sp[row][c4 * 4 + 0] = v.x; sp[row][c4 * 4 + 1] = v.y;
            sp[row][c4 * 4 + 2] = v.z; sp[row][c4 * 4 + 3] = v.w;
        }
        __syncthreads();
#pragma unroll 4
        for (int k = 0; k < 128; ++k) {
            float t0 = st[qi][k], t1 = st[qi + 1][k];
            float p0 = sp[ni][k], p1 = sp[ni + 1][k], p2 = sp[ni + 2][k], p3 = sp[ni + 3][k];
            acc[0][0] += t0 * p0; acc[0][1] += t0 * p1; acc[0][2] += t0 * p2; acc[0][3] += t0 * p3;
            acc[1][0] += t1 * p0; acc[1][1] += t1 * p1; acc[1][2] += t1 * p2; acc[1][3] += t1 * p3;
        }
        __syncthreads();
    }
#pragma unroll
    for (int iq = 0; iq < 2; ++iq) {
        int q = q0 + qi + iq;
        float w = W2[b * TQN + q];
        float4 o;
        o.x = acc[iq][0] * w; o.y = acc[iq][1] * w; o.z = acc[iq][2] * w; o.w = acc[iq][3] * w;
        *reinterpret_cast<float4*>(&sim[((size_t)b * TQN + q) * NTT + ni]) = o;
    }
}

// ---------------------------------------------------------------------------
extern "C" void kernel_launch(void* const* d_in, const int* in_sizes, int n_in,
                              void* d_out, int out_size, void* d_ws, size_t ws_size,
                              hipStream_t stream) {
    const float* reps = (const float*)d_in[0];
    const float* sup  = (const float*)d_in[1];
    const float* tgt  = (const float*)d_in[4];
    const float* l1w1 = (const float*)d_in[5];
    const float* l1b1 = (const float*)d_in[6];
    const float* l1w2 = (const float*)d_in[7];
    const float* l1b2 = (const float*)d_in[8];
    const float* l2w1 = (const float*)d_in[9];
    const float* l2b1 = (const float*)d_in[10];
    const float* l2w2 = (const float*)d_in[11];
    const float* l2b2 = (const float*)d_in[12];
    const float* fw1  = (const float*)d_in[13];
    const float* fb1  = (const float*)d_in[14];
    const float* fw2  = (const float*)d_in[15];
    const float* fb2  = (const float*)d_in[16];

    float* out    = (float*)d_out;
    float* simO   = out;                                  // (B,TQ,NT)
    float* protoO = out + (size_t)BB * TQN * NTT;         // (B,NT,D)

    float* w = (float*)d_ws;
    float* testM = w; w += (size_t)BB * TQN * DD;         // 6291456
    float* U     = w; w += (size_t)BB * SS * TQN;         // 131072
    float* Umax  = w; w += 64;
    float* Umin  = w; w += 64;
    float* Usum  = w; w += 64;
    float* cmaxp = w; w += 64;
    float* cminp = w; w += 64;
    float* csump = w; w += 64;
    float* h1m   = w; w += BB * MID1;
    float* h1a   = w; w += BB * MID1;
    float* y1    = w; w += BB * NKK;
    float* W1    = w; w += BB * NKK;
    float* h2m   = w; w += BB * MID2;
    float* h2a   = w; w += BB * MID2;
    float* y2    = w; w += BB * TQN;
    float* W2    = w; w += BB * TQN;

    k_mean_u<<<BB * TQN, 192, 0, stream>>>((const nt_f4*)reps, (float4*)testM,
                                           (const float4*)sup, U);
    k_stats<<<BB * SS, 256, 0, stream>>>(U, tgt, Umax, Umin, Usum, cmaxp, cminp, csump);
    k_mlp_h<<<BB * 4 + BB * 7, 256, 0, stream>>>(tgt, Umax, Umin, Usum,
                                                 U, cmaxp, cminp, csump,
                                                 l1w1, l1b1, l2w1, l2b1,
                                                 h1m, h1a, h2m, h2a);
    k_mlp_out<<<BB * 8 + BB * 16, 256, 0, stream>>>(h1m, h1a, h2m, h2a,
                                                    l1w2, l1b2, l2w2, l2b2,
                                                    fw1, fb1, fw2, fb2, y1, y2);
    k_softmax2<<<2 * BB, 256, 0, stream>>>(y1, W1, y2, W2);
    k_proto<<<BB * NTT, 256, 0, stream>>>(W1, tgt, sup, protoO);
    k_sim<<<BB * (TQN / 32), 256, 0, stream>>>(testM, protoO, W2, simO);
}

// Round 6
// 179.569 us; speedup vs baseline: 2.1720x; 2.1720x over previous
//
#include <hip/hip_runtime.h>
#include <hip/hip_bf16.h>
#include <float.h>
#include <math.h>

// dims
#define BB   4
#define SS   16
#define TQN  2048
#define DD   768
#define NTT  64
#define NKK  1024     // SS*NTT
#define MID1 204
#define MID2 409

typedef float nt_f4 __attribute__((ext_vector_type(4)));

// ---------------------------------------------------------------------------
// K1: fused  testM = mean_s(reps)  AND  U[b,s,q] = sup[b,s,:].testM[b,q,:]
// ---------------------------------------------------------------------------
__global__ __launch_bounds__(192) void k_mean_u(const nt_f4* __restrict__ reps,
                                                float4* __restrict__ testM,
                                                const float4* __restrict__ sup,
                                                float* __restrict__ U) {
    const int QD4 = TQN * DD / 4;
    int bq = blockIdx.x;
    int b = bq >> 11, q = bq & 2047;
    int t = threadIdx.x;
    const nt_f4* base = reps + ((size_t)b * SS * TQN + q) * (DD / 4) + t;
    nt_f4 acc = {0.f, 0.f, 0.f, 0.f};
#pragma unroll
    for (int s = 0; s < SS; ++s)
        acc += __builtin_nontemporal_load(&base[(size_t)s * QD4]);
    acc *= (1.f / SS);
    float4 av; av.x = acc.x; av.y = acc.y; av.z = acc.z; av.w = acc.w;
    testM[((size_t)b * TQN + q) * (DD / 4) + t] = av;

    float part[SS];
#pragma unroll
    for (int s = 0; s < SS; ++s) {
        float4 sv = sup[((size_t)b * SS + s) * (DD / 4) + t];
        part[s] = av.x * sv.x + av.y * sv.y + av.z * sv.z + av.w * sv.w;
    }
    __shared__ float rbuf[3][SS];
    int lane = t & 63, wv = t >> 6;
#pragma unroll
    for (int s = 0; s < SS; ++s) {
        float v = part[s];
        for (int o = 32; o; o >>= 1) v += __shfl_down(v, o, 64);
        if (lane == 0) rbuf[wv][s] = v;
    }
    __syncthreads();
    if (t < SS)
        U[((size_t)b * SS + t) * TQN + q] = rbuf[0][t] + rbuf[1][t] + rbuf[2][t];
}

// ---------------------------------------------------------------------------
// K2: per-(b,s) stats of U over q, and of tgt over n
// ---------------------------------------------------------------------------
__global__ __launch_bounds__(256) void k_stats(const float* __restrict__ U,
                                               const float* __restrict__ tgt,
                                               float* __restrict__ Umax, float* __restrict__ Umin,
                                               float* __restrict__ Usum,
                                               float* __restrict__ cmax, float* __restrict__ cmin,
                                               float* __restrict__ csum) {
    int bs = blockIdx.x, t = threadIdx.x;
    const float* u = U + (size_t)bs * TQN;
    float mx = -FLT_MAX, mn = FLT_MAX, sm = 0.f;
    for (int q = t; q < TQN; q += 256) {
        float v = u[q];
        mx = fmaxf(mx, v); mn = fminf(mn, v); sm += v;
    }
    int lane = t & 63, wv = t >> 6;
    for (int o = 32; o; o >>= 1) {
        mx = fmaxf(mx, __shfl_down(mx, o, 64));
        mn = fminf(mn, __shfl_down(mn, o, 64));
        sm += __shfl_down(sm, o, 64);
    }
    __shared__ float smx[4], smn[4], ssm[4];
    if (lane == 0) { smx[wv] = mx; smn[wv] = mn; ssm[wv] = sm; }
    __syncthreads();
    if (t == 0) {
        Umax[bs] = fmaxf(fmaxf(smx[0], smx[1]), fmaxf(smx[2], smx[3]));
        Umin[bs] = fminf(fminf(smn[0], smn[1]), fminf(smn[2], smn[3]));
        Usum[bs] = ssm[0] + ssm[1] + ssm[2] + ssm[3];
    }
    if (wv == 1) {
        float v = tgt[(size_t)bs * NTT + lane];
        float tmx = v, tmn = v, tsm = v;
        for (int o = 32; o; o >>= 1) {
            tmx = fmaxf(tmx, __shfl_down(tmx, o, 64));
            tmn = fminf(tmn, __shfl_down(tmn, o, 64));
            tsm += __shfl_down(tsm, o, 64);
        }
        if (lane == 0) { cmax[bs] = tmx; cmin[bs] = tmn; csum[bs] = tsm; }
    }
}

// ---------------------------------------------------------------------------
// K3: features for both branches (dense vectors for the GEMV stage)
// i in [0, BB*NKK): branch1;  i-BB*NKK in [0, BB*TQN): branch2
// ---------------------------------------------------------------------------
__global__ __launch_bounds__(256) void k_feat(const float* __restrict__ tgt,
                                              const float* __restrict__ Umax,
                                              const float* __restrict__ Umin,
                                              const float* __restrict__ Usum,
                                              const float* __restrict__ U,
                                              const float* __restrict__ cmax,
                                              const float* __restrict__ cmin,
                                              const float* __restrict__ csum,
                                              float* __restrict__ xm1, float* __restrict__ xa1,
                                              float* __restrict__ xm2, float* __restrict__ xa2) {
    int i = blockIdx.x * 256 + threadIdx.x;
    if (i < BB * NKK) {
        int b = i >> 10, bs = b * SS + ((i & 1023) >> 6);
        float c = tgt[i];
        xm1[i] = c > 0.f ? c * Umax[bs] : (c < 0.f ? c * Umin[bs] : 0.f);
        xa1[i] = c * Usum[bs] * (1.f / TQN);
    } else {
        int i2 = i - BB * NKK;
        if (i2 < BB * TQN) {
            int b = i2 >> 11, q = i2 & 2047;
            float vmax = -FLT_MAX, vsum = 0.f;
#pragma unroll
            for (int s = 0; s < SS; ++s) {
                int bs = b * SS + s;
                float u = U[(size_t)bs * TQN + q];
                float pm_ = u > 0.f ? u * cmax[bs] : (u < 0.f ? u * cmin[bs] : 0.f);
                vmax = fmaxf(vmax, pm_);
                vsum += u * csum[bs];
            }
            xm2[i2] = vmax;
            xa2[i2] = vsum * (1.f / NKK);
        }
    }
}

// ---------------------------------------------------------------------------
// K4: hidden-layer partials. blocks [0,128): br1 (b,jt<4,rc<8);
// [128,576): br2 (b,jt<7,rc<16). Each block: 128-deep r-chunk, 64-wide j-tile,
// 4 waves x 32 fully-unrolled loads -> deep MLP ILP.
// ---------------------------------------------------------------------------
#define CH 128
__global__ __launch_bounds__(256) void k_hA(const float* __restrict__ xm1,
                                            const float* __restrict__ xa1,
                                            const float* __restrict__ xm2,
                                            const float* __restrict__ xa2,
                                            const float* __restrict__ w1a,
                                            const float* __restrict__ w1b,
                                            float* __restrict__ p1m, float* __restrict__ p1a,
                                            float* __restrict__ p2m, float* __restrict__ p2a) {
    int blk = blockIdx.x, t = threadIdx.x;
    int b, jt, rc, NH, JT, RC;
    const float *w1, *xm, *xa;
    float *pm_, *pa_;
    if (blk < 128) {
        b = blk >> 5; int r_ = blk & 31; jt = r_ >> 3; rc = r_ & 7;
        NH = MID1; JT = 4; RC = 8; w1 = w1a;
        xm = xm1 + b * NKK; xa = xa1 + b * NKK; pm_ = p1m; pa_ = p1a;
    } else {
        int blk2 = blk - 128;
        b = blk2 / 112; int r_ = blk2 % 112; jt = r_ >> 4; rc = r_ & 15;
        NH = MID2; JT = 7; RC = 16; w1 = w1b;
        xm = xm2 + b * TQN; xa = xa2 + b * TQN; pm_ = p2m; pa_ = p2a;
    }
    __shared__ float sxm[CH], sxa[CH];
    int rbase = rc * CH;
    if (t < CH) { sxm[t] = xm[rbase + t]; sxa[t] = xa[rbase + t]; }
    __syncthreads();
    int lane = t & 63, wv = t >> 6;
    int j = jt * 64 + lane;
    float accm = 0.f, acca = 0.f;
    if (j < NH) {
        const float* wp = w1 + (size_t)(rbase + wv * 32) * NH + j;
#pragma unroll
        for (int rr = 0; rr < 32; ++rr) {
            float w = wp[(size_t)rr * NH];
            accm += sxm[wv * 32 + rr] * w;
            acca += sxa[wv * 32 + rr] * w;
        }
    }
    __shared__ float pm[4][64], pa[4][64];
    pm[wv][lane] = accm; pa[wv][lane] = acca;
    __syncthreads();
    if (t < 64) {
        int idx = ((b * JT + jt) * RC + rc) * 64 + t;
        pm_[idx] = pm[0][t] + pm[1][t] + pm[2][t] + pm[3][t];
        pa_[idx] = pa[0][t] + pa[1][t] + pa[2][t] + pa[3][t];
    }
}

// ---------------------------------------------------------------------------
// K5: hidden finalize: sum r-chunk partials + bias, relu.
// blocks [0,16): br1 (b,jt<4); [16,44): br2 (b,jt<7). 64 threads.
// ---------------------------------------------------------------------------
__global__ __launch_bounds__(64) void k_hB(const float* __restrict__ p1m,
                                           const float* __restrict__ p1a,
                                           const float* __restrict__ p2m,
                                           const float* __restrict__ p2a,
                                           const float* __restrict__ b1a_,
                                           const float* __restrict__ b1b_,
                                           float* __restrict__ h1m, float* __restrict__ h1a,
                                           float* __restrict__ h2m, float* __restrict__ h2a) {
    int blk = blockIdx.x, t = threadIdx.x;
    if (blk < 16) {
        int b = blk >> 2, jt = blk & 3, j = jt * 64 + t;
        if (j < MID1) {
            float m_ = 0.f, a_ = 0.f;
#pragma unroll
            for (int rc = 0; rc < 8; ++rc) {
                int idx = ((b * 4 + jt) * 8 + rc) * 64 + t;
                m_ += p1m[idx]; a_ += p1a[idx];
            }
            float bb_ = b1a_[j];
            h1m[b * MID1 + j] = fmaxf(m_ + bb_, 0.f);
            h1a[b * MID1 + j] = fmaxf(a_ + bb_, 0.f);
        }
    } else {
        int blk2 = blk - 16;
        int b = blk2 / 7, jt = blk2 % 7, j = jt * 64 + t;
        if (j < MID2) {
            float m_ = 0.f, a_ = 0.f;
#pragma unroll
            for (int rc = 0; rc < 16; ++rc) {
                int idx = ((b * 7 + jt) * 16 + rc) * 64 + t;
                m_ += p2m[idx]; a_ += p2a[idx];
            }
            float bb_ = b1b_[j];
            h2m[b * MID2 + j] = fmaxf(m_ + bb_, 0.f);
            h2a[b * MID2 + j] = fmaxf(a_ + bb_, 0.f);
        }
    }
}

// ---------------------------------------------------------------------------
// K6: out-layer partials. blocks [0,64): br1 (b,rt<8,jc<2, CHJ=102);
// [64,320): br2 (b,rt<16,jc<4, CHJ=103). 2 j-subchunks per 128-wide r-tile.
// ---------------------------------------------------------------------------
__global__ __launch_bounds__(256) void k_oA(const float* __restrict__ h1m,
                                            const float* __restrict__ h1a,
                                            const float* __restrict__ h2m,
                                            const float* __restrict__ h2a,
                                            const float* __restrict__ w2a,
                                            const float* __restrict__ w2b,
                                            float* __restrict__ q1m, float* __restrict__ q1a,
                                            float* __restrict__ q2m, float* __restrict__ q2a) {
    int blk = blockIdx.x, t = threadIdx.x;
    int b, rt, jc, NH, NOUT, RT, JC, CHJ;
    const float *hm_, *ha_, *w2;
    float *qm_, *qa_;
    if (blk < 64) {
        b = blk >> 4; int r_ = blk & 15; rt = r_ >> 1; jc = r_ & 1;
        NH = MID1; NOUT = NKK; RT = 8; JC = 2; CHJ = 102;
        hm_ = h1m + b * MID1; ha_ = h1a + b * MID1; w2 = w2a; qm_ = q1m; qa_ = q1a;
    } else {
        int blk2 = blk - 64;
        b = blk2 >> 6; int r_ = blk2 & 63; rt = r_ >> 2; jc = r_ & 3;
        NH = MID2; NOUT = TQN; RT = 16; JC = 4; CHJ = 103;
        hm_ = h2m + b * MID2; ha_ = h2a + b * MID2; w2 = w2b; qm_ = q2m; qa_ = q2a;
    }
    __shared__ float shm[104], sha[104];
    int jbase = jc * CHJ;
    if (t < CHJ) {
        int j = jbase + t;
        bool ok = j < NH;
        shm[t] = ok ? hm_[j] : 0.f;
        sha[t] = ok ? ha_[j] : 0.f;
    }
    __syncthreads();
    int rl = t & 127, jp = t >> 7;
    int r = rt * 128 + rl;
    float accm = 0.f, acca = 0.f;
#pragma unroll 4
    for (int jj = jp; jj < CHJ; jj += 2) {
        int j = jbase + jj;
        int j2 = j < NH ? j : NH - 1;           // shm is 0 there; clamp keeps addr in-bounds
        float w = w2[(size_t)j2 * NOUT + r];
        accm += shm[jj] * w; acca += sha[jj] * w;
    }
    __shared__ float qm[2][128], qa[2][128];
    qm[jp][rl] = accm; qa[jp][rl] = acca;
    __syncthreads();
    if (t < 128) {
        int idx = ((b * RT + rt) * JC + jc) * 128 + t;
        qm_[idx] = qm[0][t] + qm[1][t];
        qa_[idx] = qa[0][t] + qa[1][t];
    }
}

// ---------------------------------------------------------------------------
// K7: out finalize + fuse MLP -> y (pre-softmax).
// blocks [0,32): br1 (b,rt<8); [32,96): br2 (b,rt<16). 128 threads.
// ---------------------------------------------------------------------------
__global__ __launch_bounds__(128) void k_oB(const float* __restrict__ q1m,
                                            const float* __restrict__ q1a,
                                            const float* __restrict__ q2m,
                                            const float* __restrict__ q2a,
                                            const float* __restrict__ b2a_,
                                            const float* __restrict__ b2b_,
                                            const float* __restrict__ fw1, const float* __restrict__ fb1,
                                            const float* __restrict__ fw2, const float* __restrict__ fb2,
                                            float* __restrict__ y1, float* __restrict__ y2) {
    int blk = blockIdx.x, t = threadIdx.x;
    float f0 = fw1[0], f1 = fw1[1], fb = fb1[0], g0 = fw2[0], gb = fb2[0];
    if (blk < 32) {
        int b = blk >> 3, rt = blk & 7, r = rt * 128 + t;
        float bb_ = b2a_[r];
        float ym = bb_, ya = bb_;
#pragma unroll
        for (int jc = 0; jc < 2; ++jc) {
            int idx = ((b * 8 + rt) * 2 + jc) * 128 + t;
            ym += q1m[idx]; ya += q1a[idx];
        }
        float z = fmaxf(ya * f0 + ym * f1 + fb, 0.f);
        y1[b * NKK + r] = z * g0 + gb;
    } else {
        int blk2 = blk - 32;
        int b = blk2 >> 4, rt = blk2 & 15, r = rt * 128 + t;
        float bb_ = b2b_[r];
        float ym = bb_, ya = bb_;
#pragma unroll
        for (int jc = 0; jc < 4; ++jc) {
            int idx = ((b * 16 + rt) * 4 + jc) * 128 + t;
            ym += q2m[idx]; ya += q2a[idx];
        }
        float z = fmaxf(ya * f0 + ym * f1 + fb, 0.f);
        y2[b * TQN + r] = z * g0 + gb;
    }
}

// ---------------------------------------------------------------------------
// K8: both softmaxes. blocks 0..3 -> y1 (1024), 4..7 -> y2 (2048)
// ---------------------------------------------------------------------------
__global__ __launch_bounds__(256) void k_softmax2(const float* __restrict__ y1,
                                                  float* __restrict__ W1,
                                                  const float* __restrict__ y2,
                                                  float* __restrict__ W2) {
    int blk = blockIdx.x, t = threadIdx.x;
    const float* yr; float* Wr; int N;
    if (blk < BB) { yr = y1 + (size_t)blk * NKK; Wr = W1 + (size_t)blk * NKK; N = NKK; }
    else          { yr = y2 + (size_t)(blk - BB) * TQN; Wr = W2 + (size_t)(blk - BB) * TQN; N = TQN; }
    int lane = t & 63, wv = t >> 6;
    __shared__ float rb[4];
    float mx = -FLT_MAX;
    for (int i = t; i < N; i += 256) mx = fmaxf(mx, yr[i]);
    for (int o = 32; o; o >>= 1) mx = fmaxf(mx, __shfl_down(mx, o, 64));
    if (lane == 0) rb[wv] = mx;
    __syncthreads();
    mx = fmaxf(fmaxf(rb[0], rb[1]), fmaxf(rb[2], rb[3]));
    __syncthreads();
    float sm = 0.f;
    for (int i = t; i < N; i += 256) sm += expf(yr[i] - mx);
    for (int o = 32; o; o >>= 1) sm += __shfl_down(sm, o, 64);
    if (lane == 0) rb[wv] = sm;
    __syncthreads();
    sm = rb[0] + rb[1] + rb[2] + rb[3];
    float inv = 1.f / sm;
    for (int i = t; i < N; i += 256) Wr[i] = expf(yr[i] - mx) * inv + 1.f;
}

// ---------------------------------------------------------------------------
// K9: proto
// ---------------------------------------------------------------------------
__global__ __launch_bounds__(256) void k_proto(const float* __restrict__ W1,
                                               const float* __restrict__ tgt,
                                               const float* __restrict__ sup,
                                               float* __restrict__ proto) {
    int bn = blockIdx.x;
    int b = bn >> 6, n = bn & 63;
    int t = threadIdx.x;
    float a0 = 0.f, a1 = 0.f, a2 = 0.f, cnt = 0.f;
#pragma unroll
    for (int s = 0; s < SS; ++s) {
        float tg = tgt[((size_t)b * SS + s) * NTT + n];
        float coef = W1[b * NKK + s * NTT + n] * tg;
        const float* sv = sup + ((size_t)b * SS + s) * DD;
        a0 += coef * sv[t];
        a1 += coef * sv[t + 256];
        a2 += coef * sv[t + 512];
        cnt += tg;
    }
    float inv = 1.f / (cnt + 1e-4f);
    float* p = proto + (size_t)bn * DD;
    p[t] = a0 * inv; p[t + 256] = a1 * inv; p[t + 512] = a2 * inv;
}

// ---------------------------------------------------------------------------
// K10: sim[b,q,n] = W2[b,q] * (testM[b,q,:] . proto[b,n,:])
// ---------------------------------------------------------------------------
__global__ __launch_bounds__(256) void k_sim(const float* __restrict__ testM,
                                             const float* __restrict__ proto,
                                             const float* __restrict__ W2,
                                             float* __restrict__ sim) {
    int bq = blockIdx.x;
    int b = bq / (TQN / 32), q0 = (bq % (TQN / 32)) * 32;
    __shared__ float st[32][129];
    __shared__ float sp[64][129];
    int t = threadIdx.x;
    int qi = (t >> 4) * 2;
    int ni = (t & 15) * 4;
    float acc[2][4] = {};
    for (int kc = 0; kc < DD; kc += 128) {
        for (int i = t; i < 32 * 32; i += 256) {
            int row = i >> 5, c4 = i & 31;
            float4 v = *reinterpret_cast<const float4*>(
                &testM[((size_t)b * TQN + q0 + row) * DD + kc + c4 * 4]);
            st[row][c4 * 4 + 0] = v.x; st[row][c4 * 4 + 1] = v.y;
            st[row][c4 * 4 + 2] = v.z; st[row][c4 * 4 + 3] = v.w;
        }
        for (int i = t; i < 64 * 32; i += 256) {
            int row = i >> 5, c4 = i & 31;
            float4 v = *reinterpret_cast<const float4*>(
                &proto[((size_t)b * NTT + row) * DD + kc + c4 * 4]);
            sp[row][c4 * 4 + 0] = v.x; sp[row][c4 * 4 + 1] = v.y;
            sp[row][c4 * 4 + 2] = v.z; sp[row][c4 * 4 + 3] = v.w;
        }
        __syncthreads();
#pragma unroll 4
        for (int k = 0; k < 128; ++k) {
            float t0 = st[qi][k], t1 = st[qi + 1][k];
            float p0 = sp[ni][k], p1 = sp[ni + 1][k], p2 = sp[ni + 2][k], p3 = sp[ni + 3][k];
            acc[0][0] += t0 * p0; acc[0][1] += t0 * p1; acc[0][2] += t0 * p2; acc[0][3] += t0 * p3;
            acc[1][0] += t1 * p0; acc[1][1] += t1 * p1; acc[1][2] += t1 * p2; acc[1][3] += t1 * p3;
        }
        __syncthreads();
    }
#pragma unroll
    for (int iq = 0; iq < 2; ++iq) {
        int q = q0 + qi + iq;
        float w = W2[b * TQN + q];
        float4 o;
        o.x = acc[iq][0] * w; o.y = acc[iq][1] * w; o.z = acc[iq][2] * w; o.w = acc[iq][3] * w;
        *reinterpret_cast<float4*>(&sim[((size_t)b * TQN + q) * NTT + ni]) = o;
    }
}

// ---------------------------------------------------------------------------
extern "C" void kernel_launch(void* const* d_in, const int* in_sizes, int n_in,
                              void* d_out, int out_size, void* d_ws, size_t ws_size,
                              hipStream_t stream) {
    const float* reps = (const float*)d_in[0];
    const float* sup  = (const float*)d_in[1];
    const float* tgt  = (const float*)d_in[4];
    const float* l1w1 = (const float*)d_in[5];
    const float* l1b1 = (const float*)d_in[6];
    const float* l1w2 = (const float*)d_in[7];
    const float* l1b2 = (const float*)d_in[8];
    const float* l2w1 = (const float*)d_in[9];
    const float* l2b1 = (const float*)d_in[10];
    const float* l2w2 = (const float*)d_in[11];
    const float* l2b2 = (const float*)d_in[12];
    const float* fw1  = (const float*)d_in[13];
    const float* fb1  = (const float*)d_in[14];
    const float* fw2  = (const float*)d_in[15];
    const float* fb2  = (const float*)d_in[16];

    float* out    = (float*)d_out;
    float* simO   = out;
    float* protoO = out + (size_t)BB * TQN * NTT;

    float* w = (float*)d_ws;
    float* testM = w; w += (size_t)BB * TQN * DD;
    float* U     = w; w += (size_t)BB * SS * TQN;
    float* Umax  = w; w += 64;
    float* Umin  = w; w += 64;
    float* Usum  = w; w += 64;
    float* cmaxp = w; w += 64;
    float* cminp = w; w += 64;
    float* csump = w; w += 64;
    float* xm1   = w; w += BB * NKK;
    float* xa1   = w; w += BB * NKK;
    float* xm2   = w; w += BB * TQN;
    float* xa2   = w; w += BB * TQN;
    float* p1m   = w; w += BB * 4 * 8 * 64;
    float* p1a   = w; w += BB * 4 * 8 * 64;
    float* p2m   = w; w += BB * 7 * 16 * 64;
    float* p2a   = w; w += BB * 7 * 16 * 64;
    float* h1m   = w; w += BB * MID1;
    float* h1a   = w; w += BB * MID1;
    float* h2m   = w; w += BB * MID2;
    float* h2a   = w; w += BB * MID2;
    float* q1m   = w; w += BB * 8 * 2 * 128;
    float* q1a   = w; w += BB * 8 * 2 * 128;
    float* q2m   = w; w += BB * 16 * 4 * 128;
    float* q2a   = w; w += BB * 16 * 4 * 128;
    float* y1    = w; w += BB * NKK;
    float* W1    = w; w += BB * NKK;
    float* y2    = w; w += BB * TQN;
    float* W2    = w; w += BB * TQN;

    k_mean_u<<<BB * TQN, 192, 0, stream>>>((const nt_f4*)reps, (float4*)testM,
                                           (const float4*)sup, U);
    k_stats<<<BB * SS, 256, 0, stream>>>(U, tgt, Umax, Umin, Usum, cmaxp, cminp, csump);
    k_feat<<<(BB * NKK + BB * TQN) / 256, 256, 0, stream>>>(tgt, Umax, Umin, Usum,
                                                            U, cmaxp, cminp, csump,
                                                            xm1, xa1, xm2, xa2);
    k_hA<<<128 + 448, 256, 0, stream>>>(xm1, xa1, xm2, xa2, l1w1, l2w1,
                                        p1m, p1a, p2m, p2a);
    k_hB<<<44, 64, 0, stream>>>(p1m, p1a, p2m, p2a, l1b1, l2b1,
                                h1m, h1a, h2m, h2a);
    k_oA<<<64 + 256, 256, 0, stream>>>(h1m, h1a, h2m, h2a, l1w2, l2w2,
                                       q1m, q1a, q2m, q2a);
    k_oB<<<32 + 64, 128, 0, stream>>>(q1m, q1a, q2m, q2a, l1b2, l2b2,
                                      fw1, fb1, fw2, fb2, y1, y2);
    k_softmax2<<<2 * BB, 256, 0, stream>>>(y1, W1, y2, W2);
    k_proto<<<BB * NTT, 256, 0, stream>>>(W1, tgt, sup, protoO);
    k_sim<<<BB * (TQN / 32), 256, 0, stream>>>(testM, protoO, W2, simO);
}